// Round 6
// baseline (1425.045 us; speedup 1.0000x reference)
//
#include <hip/hip_runtime.h>

#define NEG_SLOPE 0.2f

typedef __attribute__((ext_vector_type(4))) float floatx4;
typedef __attribute__((ext_vector_type(8))) short shortx8;

__device__ __forceinline__ unsigned short f2bf(float f) {
  union { float f; unsigned int u; } v;
  v.f = f;
  unsigned int r = (v.u + 0x7FFFu + ((v.u >> 16) & 1u)) >> 16;
  return (unsigned short)r;
}
__device__ __forceinline__ float bf2f(unsigned short u) {
  union { unsigned int u; float f; } v;
  v.u = (unsigned int)u << 16;
  return v.f;
}
__device__ __forceinline__ void store_out(float* p, float v) { *p = v; }
__device__ __forceinline__ void store_out(unsigned short* p, float v) { *p = f2bf(v); }

// ---------------- edge index width detection (int32 vs int64) ----------------
__device__ __forceinline__ int load_edge(const void* ei, long idx, int is64) {
  if (is64) return (int)((const long long*)ei)[idx];
  return ((const int*)ei)[idx];
}

__global__ void detect64_kernel(const unsigned int* __restrict__ p, int* __restrict__ flag) {
  int is64 = 1;
  for (int i = 0; i < 32; ++i)
    if (p[2 * i + 1] != 0u) is64 = 0;
  *flag = is64;
}

// ---------------- CSR build ----------------
__global__ void init_cnt_kernel(int* __restrict__ cnt, int n) {
  int i = blockIdx.x * blockDim.x + threadIdx.x;
  if (i < n) cnt[i] = 1;  // self-loop
}

__global__ void count_kernel(const void* __restrict__ ei, const int* __restrict__ flag, int E,
                             int* __restrict__ cnt) {
  int e = blockIdx.x * blockDim.x + threadIdx.x;
  if (e >= E) return;
  int is64 = *flag;
  int d = load_edge(ei, (long)E + e, is64);
  atomicAdd(&cnt[d], 1);
}

__global__ __launch_bounds__(1024) void scan_kernel(const int* __restrict__ cnt,
                                                    int* __restrict__ offs, int n) {
  __shared__ int partial[1024];
  int t = threadIdx.x;
  int per = (n + 1023) / 1024;
  int beg = t * per;
  int end = min(beg + per, n);
  int sum = 0;
  for (int i = beg; i < end; ++i) sum += cnt[i];
  partial[t] = sum;
  __syncthreads();
  for (int d = 1; d < 1024; d <<= 1) {
    int v = (t >= d) ? partial[t - d] : 0;
    __syncthreads();
    partial[t] += v;
    __syncthreads();
  }
  int excl = (t == 0) ? 0 : partial[t - 1];
  for (int i = beg; i < end; ++i) { offs[i] = excl; excl += cnt[i]; }
  if (t == 1023) offs[n] = partial[1023];
}

__global__ void init_self_kernel(const int* __restrict__ offs, int* __restrict__ srcs,
                                 int* __restrict__ fill, int n) {
  int i = blockIdx.x * blockDim.x + threadIdx.x;
  if (i < n) { srcs[offs[i]] = i; fill[i] = 1; }
}

__global__ void scatter_kernel(const void* __restrict__ ei, const int* __restrict__ flag, int E,
                               const int* __restrict__ offs, int* __restrict__ fill,
                               int* __restrict__ srcs) {
  int e = blockIdx.x * blockDim.x + threadIdx.x;
  if (e >= E) return;
  int is64 = *flag;
  int s = load_edge(ei, e, is64);
  int d = load_edge(ei, (long)E + e, is64);
  int pos = offs[d] + atomicAdd(&fill[d], 1);
  srcs[pos] = s;
}

// ---------------- casts ----------------
__global__ __launch_bounds__(256) void cast_pad_kernel(const float* __restrict__ in,
                                                       unsigned short* __restrict__ out, int M,
                                                       int K, int Kpad) {
  long idx = (long)blockIdx.x * 256 + threadIdx.x;
  int cpr = Kpad >> 2;
  if (idx >= (long)M * cpr) return;
  int r = (int)(idx / cpr);
  int kc = (int)(idx - (long)r * cpr);
  int k = kc << 2;
  float4 v = make_float4(0.f, 0.f, 0.f, 0.f);
  if (k < K) v = *(const float4*)&in[(long)r * K + k];
  ushort4 o;
  o.x = f2bf(v.x); o.y = f2bf(v.y); o.z = f2bf(v.z); o.w = f2bf(v.w);
  *(ushort4*)&out[(long)r * Kpad + k] = o;
}

__global__ __launch_bounds__(256) void transpose_cast_kernel(const float* __restrict__ in,
                                                             unsigned short* __restrict__ out,
                                                             int K, int N, int Kpad) {
  __shared__ float tile[32][33];
  int kb = blockIdx.x * 32;
  int nb = blockIdx.y * 32;
  int tx = threadIdx.x & 31;
  int ty = threadIdx.x >> 5;
#pragma unroll
  for (int i = 0; i < 32; i += 8) {
    int k = kb + ty + i;
    tile[ty + i][tx] = (k < K) ? in[(long)k * N + nb + tx] : 0.f;
  }
  __syncthreads();
#pragma unroll
  for (int i = 0; i < 32; i += 8) {
    int n = nb + ty + i;
    out[(long)n * Kpad + kb + tx] = f2bf(tile[tx][ty + i]);
  }
}

// ---------------- bf16 MFMA GEMM — LDS-free, barrier-free ----------------
// C[M,N] = A[M,K] * Bt[N,K]^T. Each wave owns a 64x64 output tile and loads
// its MFMA fragments DIRECTLY global->VGPR: for 16x16x32_bf16 the A-operand
// lane layout A[m=l16][k=quad*8+j] makes each lane's fragment a contiguous
// 16 B load (wave = 16 rows x 64 B segments, coalesced). No LDS, no
// __syncthreads -> no barrier convoy; waves self-stagger and prefetch depth-1
// (2x-unrolled K) hides L2 latency. Cost: 2x L2-side fragment traffic vs LDS
// sharing (~4 GB/GEMM at 34.5 TB/s L2 ~= 117 us floor; MFMA floor 63 us).
// Requires K%64==0, N%128==0, A allocated to gridDim.y*128 rows.
template <typename OT>
__global__ __launch_bounds__(256) void mfma_gemm_kernel(const unsigned short* __restrict__ A,
                                                        const unsigned short* __restrict__ Bt,
                                                        OT* __restrict__ C, int M, int N, int K) {
  int tid = threadIdx.x;
  int lane = tid & 63;
  int w = tid >> 6;
  int wm = w & 1, wn = w >> 1;
  int bc = blockIdx.x * 128;  // N-tile fastest (L2-friendly rounds)
  int bm = blockIdx.y * 128;
  int quad = lane >> 4, l16 = lane & 15;

  const unsigned short* pA = A + (long)(bm + wm * 64 + l16) * K + quad * 8;
  const unsigned short* pB = Bt + (long)(bc + wn * 64 + l16) * K + quad * 8;
  const long rs = (long)16 * K;  // 16-row stride (elements)

  floatx4 acc[4][4];
#pragma unroll
  for (int i = 0; i < 4; ++i)
#pragma unroll
    for (int j = 0; j < 4; ++j) acc[i][j] = (floatx4){0.f, 0.f, 0.f, 0.f};

  shortx8 ax[4], bx[4], ay[4], by[4];
#pragma unroll
  for (int i = 0; i < 4; ++i) {
    ax[i] = *(const shortx8*)(pA + i * rs);
    bx[i] = *(const shortx8*)(pB + i * rs);
  }

  for (int k0 = 0; k0 < K; k0 += 64) {
    // prefetch half-tile Y (k0+32) — flies during MFMAs on X
#pragma unroll
    for (int i = 0; i < 4; ++i) {
      ay[i] = *(const shortx8*)(pA + k0 + 32 + i * rs);
      by[i] = *(const shortx8*)(pB + k0 + 32 + i * rs);
    }
#pragma unroll
    for (int i = 0; i < 4; ++i)
#pragma unroll
      for (int j = 0; j < 4; ++j)
        acc[i][j] = __builtin_amdgcn_mfma_f32_16x16x32_bf16(ax[i], bx[j], acc[i][j], 0, 0, 0);
    if (k0 + 64 < K) {
      // prefetch half-tile X (k0+64) — flies during MFMAs on Y
#pragma unroll
      for (int i = 0; i < 4; ++i) {
        ax[i] = *(const shortx8*)(pA + k0 + 64 + i * rs);
        bx[i] = *(const shortx8*)(pB + k0 + 64 + i * rs);
      }
    }
#pragma unroll
    for (int i = 0; i < 4; ++i)
#pragma unroll
      for (int j = 0; j < 4; ++j)
        acc[i][j] = __builtin_amdgcn_mfma_f32_16x16x32_bf16(ay[i], by[j], acc[i][j], 0, 0, 0);
  }

  // epilogue: C/D layout col=lane&15, row=quad*4+reg
  int orow0 = bm + wm * 64 + quad * 4;
  int ocol0 = bc + wn * 64 + l16;
#pragma unroll
  for (int i = 0; i < 4; ++i)
#pragma unroll
    for (int j = 0; j < 4; ++j)
#pragma unroll
      for (int r = 0; r < 4; ++r) {
        int rr = orow0 + i * 16 + r;
        if (rr < M) store_out(&C[(long)rr * N + ocol0 + j * 16], acc[i][j][r]);
      }
}

// ---------------- attention coefficients from bf16 h ----------------
__global__ __launch_bounds__(256) void att_coef_kernel(const unsigned short* __restrict__ h,
                                                       const float* __restrict__ att_s,
                                                       const float* __restrict__ att_d,
                                                       float* __restrict__ a_s,
                                                       float* __restrict__ a_d, int n, int H,
                                                       int C) {
  int wave = (int)((blockIdx.x * blockDim.x + threadIdx.x) >> 6);
  int lane = threadIdx.x & 63;
  if (wave >= n) return;
  const unsigned short* row = h + (long)wave * H * C;
  for (int hh = 0; hh < H; ++hh) {
    float s = 0.f, d = 0.f;
    for (int c = lane; c < C; c += 64) {
      float v = bf2f(row[hh * C + c]);
      s += v * att_s[hh * C + c];
      d += v * att_d[hh * C + c];
    }
#pragma unroll
    for (int o = 32; o > 0; o >>= 1) {
      s += __shfl_down(s, o, 64);
      d += __shfl_down(d, o, 64);
    }
    if (lane == 0) {
      a_s[(long)wave * H + hh] = s;
      a_d[(long)wave * H + hh] = d;
    }
  }
}

// ---------------- per-(dst,head) segment softmax over CSR ----------------
__global__ void edge_softmax_kernel(const float* __restrict__ a_src,
                                    const float* __restrict__ a_dst,
                                    const int* __restrict__ offs, const int* __restrict__ srcs,
                                    float* __restrict__ alpha, int n, int H) {
  int idx = blockIdx.x * blockDim.x + threadIdx.x;
  if (idx >= n * H) return;
  int dstn = idx / H;
  int hh = idx - dstn * H;
  int beg = offs[dstn], end = offs[dstn + 1];
  float ad = a_dst[idx];
  float m = -1e30f;
  for (int j = beg; j < end; ++j) {
    float e = a_src[srcs[j] * H + hh] + ad;
    e = e > 0.f ? e : NEG_SLOPE * e;
    m = fmaxf(m, e);
  }
  float ssum = 0.f;
  for (int j = beg; j < end; ++j) {
    float e = a_src[srcs[j] * H + hh] + ad;
    e = e > 0.f ? e : NEG_SLOPE * e;
    float ex = __expf(e - m);
    alpha[(long)j * H + hh] = ex;
    ssum += ex;
  }
  float inv = 1.f / ssum;
  for (int j = beg; j < end; ++j) alpha[(long)j * H + hh] *= inv;
}

// ---------------- layer-1 aggregation: bf16 h -> bf16 x2, 16B vector loads ----------------
__global__ __launch_bounds__(320) void aggregate1_kernel(const unsigned short* __restrict__ h,
                                                         const float* __restrict__ alpha,
                                                         const int* __restrict__ offs,
                                                         const int* __restrict__ srcs,
                                                         const float* __restrict__ bias,
                                                         unsigned short* __restrict__ out, int H,
                                                         int C, int HC) {
  int dstn = blockIdx.x;
  int t = threadIdx.x;
  int beg = offs[dstn], end = offs[dstn + 1];
  int nf8 = HC >> 3;
  for (int fid = t; fid < nf8; fid += blockDim.x) {
    int hh = (fid << 3) / C;
    float acc[8];
#pragma unroll
    for (int i = 0; i < 8; ++i) acc[i] = 0.f;
    for (int j = beg; j < end; ++j) {
      int s = srcs[j];
      float al = alpha[(long)j * H + hh];
      shortx8 r = ((const shortx8*)(h + (long)s * HC))[fid];
#pragma unroll
      for (int i = 0; i < 8; ++i) acc[i] = fmaf(al, bf2f((unsigned short)r[i]), acc[i]);
    }
    shortx8 o;
#pragma unroll
    for (int i = 0; i < 8; ++i) {
      float bb = bias[(fid << 3) + i];
      o[i] = (short)f2bf(fmaxf(acc[i] + bb, 0.f));
    }
    ((shortx8*)(out + (long)dstn * HC))[fid] = o;
  }
}

// ---------------- layer-2 aggregation with head-mean: bf16 h -> fp32 out ----------------
__global__ __launch_bounds__(128) void aggregate2_kernel(const unsigned short* __restrict__ h,
                                                         const float* __restrict__ alpha,
                                                         const int* __restrict__ offs,
                                                         const int* __restrict__ srcs,
                                                         const float* __restrict__ bias,
                                                         float* __restrict__ out, int H, int C) {
  int dstn = blockIdx.x;
  int c = threadIdx.x;
  if (c >= C) return;
  int beg = offs[dstn], end = offs[dstn + 1];
  int HC = H * C;
  float acc = 0.f;
  for (int j = beg; j < end; ++j) {
    int s = srcs[j];
    const unsigned short* row = h + (long)s * HC;
    const float* al = alpha + (long)j * H;
#pragma unroll 5
    for (int hh = 0; hh < H; ++hh) acc = fmaf(al[hh], bf2f(row[hh * C + c]), acc);
  }
  float v = acc * (1.f / (float)H) + bias[c];
  out[(long)dstn * C + c] = v > 0.f ? v : 0.f;
}

// ---------------- host ----------------
static inline size_t align256(size_t x) { return (x + 255) & ~(size_t)255; }

extern "C" void kernel_launch(void* const* d_in, const int* in_sizes, int n_in, void* d_out,
                              int out_size, void* d_ws, size_t ws_size, hipStream_t stream) {
  const float* x        = (const float*)d_in[0];
  const void*  ei       = d_in[1];
  const float* W1       = (const float*)d_in[2];
  const float* att_src1 = (const float*)d_in[3];
  const float* att_dst1 = (const float*)d_in[4];
  const float* b1       = (const float*)d_in[5];
  const float* W2       = (const float*)d_in[6];
  const float* att_src2 = (const float*)d_in[7];
  const float* att_dst2 = (const float*)d_in[8];
  const float* b2       = (const float*)d_in[9];
  float* out = (float*)d_out;

  const int C2  = in_sizes[9];       // 128
  const int H   = in_sizes[7] / C2;  // 20
  const int HC1 = in_sizes[5];       // 2560
  const int C1  = HC1 / H;           // 128
  const int G   = in_sizes[2] / HC1; // 2000
  const int Nn  = in_sizes[0] / G;   // 10000
  const int E   = in_sizes[1] / 2;   // 100000
  const int HC2 = H * C2;            // 2560
  const int Et  = E + Nn;
  const int Mpad = ((Nn + 127) / 128) * 128;
  const int K1pad = ((G + 63) / 64) * 64;  // 2048

  // workspace layout
  char* p = (char*)d_ws;
  size_t off = 0;
  unsigned short* hb  = (unsigned short*)(p + off); off = align256(off + (size_t)Mpad * (HC1 > HC2 ? HC1 : HC2) * 2);
  unsigned short* xb  = (unsigned short*)(p + off); off = align256(off + (size_t)Mpad * K1pad * 2);
  unsigned short* xb2 = (unsigned short*)(p + off); off = align256(off + (size_t)Mpad * HC1 * 2);
  unsigned short* W1t = (unsigned short*)(p + off); off = align256(off + (size_t)HC1 * K1pad * 2);
  unsigned short* W2t = (unsigned short*)(p + off); off = align256(off + (size_t)HC2 * HC1 * 2);
  float* a_s   = (float*)(p + off); off = align256(off + (size_t)Nn * H * 4);
  float* a_d   = (float*)(p + off); off = align256(off + (size_t)Nn * H * 4);
  float* alpha = (float*)(p + off); off = align256(off + (size_t)Et * H * 4);
  int* cnt     = (int*)(p + off); off = align256(off + (size_t)Nn * 4);
  int* offs    = (int*)(p + off); off = align256(off + (size_t)(Nn + 1) * 4);
  int* fill    = (int*)(p + off); off = align256(off + (size_t)Nn * 4);
  int* srcs    = (int*)(p + off); off = align256(off + (size_t)Et * 4);
  int* flag64  = (int*)(p + off); off = align256(off + 16);
  (void)ws_size; (void)n_in; (void)out_size;

  const int TB = 256;
  // CSR build
  detect64_kernel<<<1, 1, 0, stream>>>((const unsigned int*)ei, flag64);
  init_cnt_kernel<<<(Nn + TB - 1) / TB, TB, 0, stream>>>(cnt, Nn);
  count_kernel<<<(E + TB - 1) / TB, TB, 0, stream>>>(ei, flag64, E, cnt);
  scan_kernel<<<1, 1024, 0, stream>>>(cnt, offs, Nn);
  init_self_kernel<<<(Nn + TB - 1) / TB, TB, 0, stream>>>(offs, srcs, fill, Nn);
  scatter_kernel<<<(E + TB - 1) / TB, TB, 0, stream>>>(ei, flag64, E, offs, fill, srcs);

  // bf16 casts
  {
    long chunks = (long)Nn * (K1pad >> 2);
    cast_pad_kernel<<<(int)((chunks + 255) / 256), 256, 0, stream>>>(x, xb, Nn, G, K1pad);
    dim3 g1(K1pad / 32, HC1 / 32);
    transpose_cast_kernel<<<g1, 256, 0, stream>>>(W1, W1t, G, HC1, K1pad);
    dim3 g2(HC1 / 32, HC2 / 32);
    transpose_cast_kernel<<<g2, 256, 0, stream>>>(W2, W2t, HC1, HC2, HC1);
  }

  // layer 1
  {
    dim3 grid(HC1 / 128, Mpad / 128);  // N-tile fastest
    mfma_gemm_kernel<unsigned short><<<grid, 256, 0, stream>>>(xb, W1t, hb, Nn, HC1, K1pad);
  }
  att_coef_kernel<<<(Nn + 3) / 4, 256, 0, stream>>>(hb, att_src1, att_dst1, a_s, a_d, Nn, H, C1);
  edge_softmax_kernel<<<(Nn * H + TB - 1) / TB, TB, 0, stream>>>(a_s, a_d, offs, srcs, alpha, Nn, H);
  aggregate1_kernel<<<Nn, 320, 0, stream>>>(hb, alpha, offs, srcs, b1, xb2, H, C1, HC1);

  // layer 2
  {
    dim3 grid(HC2 / 128, Mpad / 128);
    mfma_gemm_kernel<unsigned short><<<grid, 256, 0, stream>>>(xb2, W2t, hb, Nn, HC2, HC1);
  }
  att_coef_kernel<<<(Nn + 3) / 4, 256, 0, stream>>>(hb, att_src2, att_dst2, a_s, a_d, Nn, H, C2);
  edge_softmax_kernel<<<(Nn * H + TB - 1) / TB, TB, 0, stream>>>(a_s, a_d, offs, srcs, alpha, Nn, H);
  aggregate2_kernel<<<Nn, 128, 0, stream>>>(hb, alpha, offs, srcs, b2, out, H, C2);
}

// Round 7
// 1300.054 us; speedup vs baseline: 1.0961x; 1.0961x over previous
//
#include <hip/hip_runtime.h>

#define NEG_SLOPE 0.2f

typedef __attribute__((ext_vector_type(4))) float floatx4;
typedef __attribute__((ext_vector_type(8))) short shortx8;

__device__ __forceinline__ unsigned short f2bf(float f) {
  union { float f; unsigned int u; } v;
  v.f = f;
  unsigned int r = (v.u + 0x7FFFu + ((v.u >> 16) & 1u)) >> 16;
  return (unsigned short)r;
}
__device__ __forceinline__ float bf2f(unsigned short u) {
  union { unsigned int u; float f; } v;
  v.u = (unsigned int)u << 16;
  return v.f;
}
__device__ __forceinline__ void store_out(float* p, float v) { *p = v; }
__device__ __forceinline__ void store_out(unsigned short* p, float v) { *p = f2bf(v); }

__device__ __forceinline__ void glds16(const unsigned short* g, unsigned short* l) {
  __builtin_amdgcn_global_load_lds((const __attribute__((address_space(1))) void*)g,
                                   (__attribute__((address_space(3))) void*)l, 16, 0, 0);
}

// ---------------- edge index width detection (int32 vs int64) ----------------
__device__ __forceinline__ int load_edge(const void* ei, long idx, int is64) {
  if (is64) return (int)((const long long*)ei)[idx];
  return ((const int*)ei)[idx];
}

__global__ void detect64_kernel(const unsigned int* __restrict__ p, int* __restrict__ flag) {
  int is64 = 1;
  for (int i = 0; i < 32; ++i)
    if (p[2 * i + 1] != 0u) is64 = 0;
  *flag = is64;
}

// ---------------- CSR build ----------------
__global__ void init_cnt_kernel(int* __restrict__ cnt, int n) {
  int i = blockIdx.x * blockDim.x + threadIdx.x;
  if (i < n) cnt[i] = 1;  // self-loop
}

__global__ void count_kernel(const void* __restrict__ ei, const int* __restrict__ flag, int E,
                             int* __restrict__ cnt) {
  int e = blockIdx.x * blockDim.x + threadIdx.x;
  if (e >= E) return;
  int is64 = *flag;
  int d = load_edge(ei, (long)E + e, is64);
  atomicAdd(&cnt[d], 1);
}

__global__ __launch_bounds__(1024) void scan_kernel(const int* __restrict__ cnt,
                                                    int* __restrict__ offs, int n) {
  __shared__ int partial[1024];
  int t = threadIdx.x;
  int per = (n + 1023) / 1024;
  int beg = t * per;
  int end = min(beg + per, n);
  int sum = 0;
  for (int i = beg; i < end; ++i) sum += cnt[i];
  partial[t] = sum;
  __syncthreads();
  for (int d = 1; d < 1024; d <<= 1) {
    int v = (t >= d) ? partial[t - d] : 0;
    __syncthreads();
    partial[t] += v;
    __syncthreads();
  }
  int excl = (t == 0) ? 0 : partial[t - 1];
  for (int i = beg; i < end; ++i) { offs[i] = excl; excl += cnt[i]; }
  if (t == 1023) offs[n] = partial[1023];
}

__global__ void init_self_kernel(const int* __restrict__ offs, int* __restrict__ srcs,
                                 int* __restrict__ fill, int n) {
  int i = blockIdx.x * blockDim.x + threadIdx.x;
  if (i < n) { srcs[offs[i]] = i; fill[i] = 1; }
}

__global__ void scatter_kernel(const void* __restrict__ ei, const int* __restrict__ flag, int E,
                               const int* __restrict__ offs, int* __restrict__ fill,
                               int* __restrict__ srcs) {
  int e = blockIdx.x * blockDim.x + threadIdx.x;
  if (e >= E) return;
  int is64 = *flag;
  int s = load_edge(ei, e, is64);
  int d = load_edge(ei, (long)E + e, is64);
  int pos = offs[d] + atomicAdd(&fill[d], 1);
  srcs[pos] = s;
}

// ---------------- casts ----------------
__global__ __launch_bounds__(256) void cast_pad_kernel(const float* __restrict__ in,
                                                       unsigned short* __restrict__ out, int M,
                                                       int K, int Kpad) {
  long idx = (long)blockIdx.x * 256 + threadIdx.x;
  int cpr = Kpad >> 2;
  if (idx >= (long)M * cpr) return;
  int r = (int)(idx / cpr);
  int kc = (int)(idx - (long)r * cpr);
  int k = kc << 2;
  float4 v = make_float4(0.f, 0.f, 0.f, 0.f);
  if (k < K) v = *(const float4*)&in[(long)r * K + k];
  ushort4 o;
  o.x = f2bf(v.x); o.y = f2bf(v.y); o.z = f2bf(v.z); o.w = f2bf(v.w);
  *(ushort4*)&out[(long)r * Kpad + k] = o;
}

__global__ __launch_bounds__(256) void transpose_cast_kernel(const float* __restrict__ in,
                                                             unsigned short* __restrict__ out,
                                                             int K, int N, int Kpad) {
  __shared__ float tile[32][33];
  int kb = blockIdx.x * 32;
  int nb = blockIdx.y * 32;
  int tx = threadIdx.x & 31;
  int ty = threadIdx.x >> 5;
#pragma unroll
  for (int i = 0; i < 32; i += 8) {
    int k = kb + ty + i;
    tile[ty + i][tx] = (k < K) ? in[(long)k * N + nb + tx] : 0.f;
  }
  __syncthreads();
#pragma unroll
  for (int i = 0; i < 32; i += 8) {
    int n = nb + ty + i;
    out[(long)n * Kpad + kb + tx] = f2bf(tile[tx][ty + i]);
  }
}

// ---------------- bf16 MFMA GEMM — wave-specialized producer/consumer ----------------
// C[M,N] = A[M,K] * Bt[N,K]^T. 5 waves: w0..3 consume (128x128 tile, 4x4 MFMA
// each), w4 produces via global_load_lds into 3 rotating LDS slots, issuing
// tile k+2 then `s_waitcnt vmcnt(32)` (retires ONLY the oldest 16 loads =
// tile k; m135 semantics) and posting a RELAXED LDS flag — no __syncthreads
// in the K-loop, so no vmcnt(0) drain ever: prefetch depth = 2 consumer
// periods. Consumers spin on flag (acquire = lgkm-only), ds_read fragments,
// release-add the slot-free counter (consumers have no in-loop VMEM, so the
// release drains nothing), then MFMA.
// Requires K%32==0, N%128==0, A allocated to gridDim.y*128 rows.
#define SLOTS 3
template <typename OT>
__global__ __launch_bounds__(320) void mfma_gemm_kernel(const unsigned short* __restrict__ A,
                                                        const unsigned short* __restrict__ Bt,
                                                        OT* __restrict__ C, int M, int N, int K) {
  __shared__ unsigned short As[SLOTS][4096];
  __shared__ unsigned short Bs[SLOTS][4096];
  __shared__ int flag[SLOTS];
  __shared__ int done[SLOTS];

  int tid = threadIdx.x;
  int lane = tid & 63;
  int w = tid >> 6;  // 0..3 consumers, 4 producer
  int bn = blockIdx.x * 128;  // N-tile fastest
  int bm = blockIdx.y * 128;
  int nk = K >> 5;

  if (tid < SLOTS) { flag[tid] = -1; done[tid] = 4; }
  __syncthreads();  // only barrier in the kernel (before pipeline starts)

  if (w == 4) {
    // ---------------- producer wave ----------------
    const unsigned short* gA0 = A + (long)(bm + lane) * K;
    const unsigned short* gA1 = A + (long)(bm + 64 + lane) * K;
    const unsigned short* gB0 = Bt + (long)(bn + lane) * K;
    const unsigned short* gB1 = Bt + (long)(bn + 64 + lane) * K;

    auto issue = [&](int k) {
      int s = k % SLOTS;
      int k0 = k << 5;
#pragma unroll
      for (int kc = 0; kc < 4; ++kc) {
        glds16(gA0 + k0 + kc * 8, &As[s][(kc * 128 + lane) * 8]);
        glds16(gA1 + k0 + kc * 8, &As[s][(kc * 128 + 64 + lane) * 8]);
        glds16(gB0 + k0 + kc * 8, &Bs[s][(kc * 128 + lane) * 8]);
        glds16(gB1 + k0 + kc * 8, &Bs[s][(kc * 128 + 64 + lane) * 8]);
      }
    };

    // prime tiles 0,1 (slots free by init)
    if (lane == 0) __hip_atomic_store(&done[0], 0, __ATOMIC_RELAXED, __HIP_MEMORY_SCOPE_WORKGROUP);
    issue(0);
    if (nk > 1) {
      if (lane == 0) __hip_atomic_store(&done[1], 0, __ATOMIC_RELAXED, __HIP_MEMORY_SCOPE_WORKGROUP);
      issue(1);
    }
    for (int k = 0; k < nk; ++k) {
      int nxt = k + 2;
      if (nxt < nk) {
        int s2 = nxt % SLOTS;
        while (__hip_atomic_load(&done[s2], __ATOMIC_ACQUIRE, __HIP_MEMORY_SCOPE_WORKGROUP) != 4)
          __builtin_amdgcn_s_sleep(1);
        if (lane == 0)
          __hip_atomic_store(&done[s2], 0, __ATOMIC_RELAXED, __HIP_MEMORY_SCOPE_WORKGROUP);
        issue(nxt);
        __builtin_amdgcn_s_waitcnt(0x8F70);  // vmcnt(32): oldest 16 (= tile k) retired
      } else if (k + 1 < nk) {
        __builtin_amdgcn_s_waitcnt(0x4F70);  // vmcnt(16)
      } else {
        __builtin_amdgcn_s_waitcnt(0x0F70);  // vmcnt(0)
      }
      if (lane == 0)
        __hip_atomic_store(&flag[k % SLOTS], k, __ATOMIC_RELAXED, __HIP_MEMORY_SCOPE_WORKGROUP);
    }
  } else {
    // ---------------- consumer waves ----------------
    int wm = w & 1, wn = w >> 1;
    int quad = lane >> 4, l16 = lane & 15;

    floatx4 acc[4][4];
#pragma unroll
    for (int i = 0; i < 4; ++i)
#pragma unroll
      for (int j = 0; j < 4; ++j) acc[i][j] = (floatx4){0.f, 0.f, 0.f, 0.f};

    int s = 0;
    for (int k = 0; k < nk; ++k) {
      while (__hip_atomic_load(&flag[s], __ATOMIC_ACQUIRE, __HIP_MEMORY_SCOPE_WORKGROUP) != k)
        __builtin_amdgcn_s_sleep(1);
      shortx8 a[4], b[4];
#pragma unroll
      for (int i = 0; i < 4; ++i) {
        a[i] = *(const shortx8*)(&As[s][(quad * 128 + wm * 64 + i * 16 + l16) * 8]);
        b[i] = *(const shortx8*)(&Bs[s][(quad * 128 + wn * 64 + i * 16 + l16) * 8]);
      }
      // release drains this wave's ds_reads, then frees the slot for the producer
      if (lane == 0)
        __hip_atomic_fetch_add(&done[s], 1, __ATOMIC_RELEASE, __HIP_MEMORY_SCOPE_WORKGROUP);
#pragma unroll
      for (int i = 0; i < 4; ++i)
#pragma unroll
        for (int j = 0; j < 4; ++j)
          acc[i][j] = __builtin_amdgcn_mfma_f32_16x16x32_bf16(a[i], b[j], acc[i][j], 0, 0, 0);
      s = (s == SLOTS - 1) ? 0 : s + 1;
    }

    // epilogue: C/D layout col=lane&15, row=quad*4+reg
    int orow0 = bm + wm * 64 + quad * 4;
    int ocol0 = bn + wn * 64 + l16;
#pragma unroll
    for (int i = 0; i < 4; ++i)
#pragma unroll
      for (int j = 0; j < 4; ++j)
#pragma unroll
        for (int r = 0; r < 4; ++r) {
          int rr = orow0 + i * 16 + r;
          if (rr < M) store_out(&C[(long)rr * N + ocol0 + j * 16], acc[i][j][r]);
        }
  }
}

// ---------------- attention coefficients from bf16 h ----------------
__global__ __launch_bounds__(256) void att_coef_kernel(const unsigned short* __restrict__ h,
                                                       const float* __restrict__ att_s,
                                                       const float* __restrict__ att_d,
                                                       float* __restrict__ a_s,
                                                       float* __restrict__ a_d, int n, int H,
                                                       int C) {
  int wave = (int)((blockIdx.x * blockDim.x + threadIdx.x) >> 6);
  int lane = threadIdx.x & 63;
  if (wave >= n) return;
  const unsigned short* row = h + (long)wave * H * C;
  for (int hh = 0; hh < H; ++hh) {
    float s = 0.f, d = 0.f;
    for (int c = lane; c < C; c += 64) {
      float v = bf2f(row[hh * C + c]);
      s += v * att_s[hh * C + c];
      d += v * att_d[hh * C + c];
    }
#pragma unroll
    for (int o = 32; o > 0; o >>= 1) {
      s += __shfl_down(s, o, 64);
      d += __shfl_down(d, o, 64);
    }
    if (lane == 0) {
      a_s[(long)wave * H + hh] = s;
      a_d[(long)wave * H + hh] = d;
    }
  }
}

// ---------------- per-(dst,head) segment softmax over CSR ----------------
__global__ void edge_softmax_kernel(const float* __restrict__ a_src,
                                    const float* __restrict__ a_dst,
                                    const int* __restrict__ offs, const int* __restrict__ srcs,
                                    float* __restrict__ alpha, int n, int H) {
  int idx = blockIdx.x * blockDim.x + threadIdx.x;
  if (idx >= n * H) return;
  int dstn = idx / H;
  int hh = idx - dstn * H;
  int beg = offs[dstn], end = offs[dstn + 1];
  float ad = a_dst[idx];
  float m = -1e30f;
  for (int j = beg; j < end; ++j) {
    float e = a_src[srcs[j] * H + hh] + ad;
    e = e > 0.f ? e : NEG_SLOPE * e;
    m = fmaxf(m, e);
  }
  float ssum = 0.f;
  for (int j = beg; j < end; ++j) {
    float e = a_src[srcs[j] * H + hh] + ad;
    e = e > 0.f ? e : NEG_SLOPE * e;
    float ex = __expf(e - m);
    alpha[(long)j * H + hh] = ex;
    ssum += ex;
  }
  float inv = 1.f / ssum;
  for (int j = beg; j < end; ++j) alpha[(long)j * H + hh] *= inv;
}

// ---------------- layer-1 aggregation: bf16 h -> bf16 x2, 16B vector loads ----------------
__global__ __launch_bounds__(320) void aggregate1_kernel(const unsigned short* __restrict__ h,
                                                         const float* __restrict__ alpha,
                                                         const int* __restrict__ offs,
                                                         const int* __restrict__ srcs,
                                                         const float* __restrict__ bias,
                                                         unsigned short* __restrict__ out, int H,
                                                         int C, int HC) {
  int dstn = blockIdx.x;
  int t = threadIdx.x;
  int beg = offs[dstn], end = offs[dstn + 1];
  int nf8 = HC >> 3;
  for (int fid = t; fid < nf8; fid += blockDim.x) {
    int hh = (fid << 3) / C;
    float acc[8];
#pragma unroll
    for (int i = 0; i < 8; ++i) acc[i] = 0.f;
    for (int j = beg; j < end; ++j) {
      int s = srcs[j];
      float al = alpha[(long)j * H + hh];
      shortx8 r = ((const shortx8*)(h + (long)s * HC))[fid];
#pragma unroll
      for (int i = 0; i < 8; ++i) acc[i] = fmaf(al, bf2f((unsigned short)r[i]), acc[i]);
    }
    shortx8 o;
#pragma unroll
    for (int i = 0; i < 8; ++i) {
      float bb = bias[(fid << 3) + i];
      o[i] = (short)f2bf(fmaxf(acc[i] + bb, 0.f));
    }
    ((shortx8*)(out + (long)dstn * HC))[fid] = o;
  }
}

// ---------------- layer-2 aggregation with head-mean: bf16 h -> fp32 out ----------------
__global__ __launch_bounds__(128) void aggregate2_kernel(const unsigned short* __restrict__ h,
                                                         const float* __restrict__ alpha,
                                                         const int* __restrict__ offs,
                                                         const int* __restrict__ srcs,
                                                         const float* __restrict__ bias,
                                                         float* __restrict__ out, int H, int C) {
  int dstn = blockIdx.x;
  int c = threadIdx.x;
  if (c >= C) return;
  int beg = offs[dstn], end = offs[dstn + 1];
  int HC = H * C;
  float acc = 0.f;
  for (int j = beg; j < end; ++j) {
    int s = srcs[j];
    const unsigned short* row = h + (long)s * HC;
    const float* al = alpha + (long)j * H;
#pragma unroll 5
    for (int hh = 0; hh < H; ++hh) acc = fmaf(al[hh], bf2f(row[hh * C + c]), acc);
  }
  float v = acc * (1.f / (float)H) + bias[c];
  out[(long)dstn * C + c] = v > 0.f ? v : 0.f;
}

// ---------------- host ----------------
static inline size_t align256(size_t x) { return (x + 255) & ~(size_t)255; }

extern "C" void kernel_launch(void* const* d_in, const int* in_sizes, int n_in, void* d_out,
                              int out_size, void* d_ws, size_t ws_size, hipStream_t stream) {
  const float* x        = (const float*)d_in[0];
  const void*  ei       = d_in[1];
  const float* W1       = (const float*)d_in[2];
  const float* att_src1 = (const float*)d_in[3];
  const float* att_dst1 = (const float*)d_in[4];
  const float* b1       = (const float*)d_in[5];
  const float* W2       = (const float*)d_in[6];
  const float* att_src2 = (const float*)d_in[7];
  const float* att_dst2 = (const float*)d_in[8];
  const float* b2       = (const float*)d_in[9];
  float* out = (float*)d_out;

  const int C2  = in_sizes[9];       // 128
  const int H   = in_sizes[7] / C2;  // 20
  const int HC1 = in_sizes[5];       // 2560
  const int C1  = HC1 / H;           // 128
  const int G   = in_sizes[2] / HC1; // 2000
  const int Nn  = in_sizes[0] / G;   // 10000
  const int E   = in_sizes[1] / 2;   // 100000
  const int HC2 = H * C2;            // 2560
  const int Et  = E + Nn;
  const int Mpad = ((Nn + 127) / 128) * 128;
  const int K1pad = ((G + 31) / 32) * 32;  // 2048

  // workspace layout
  char* p = (char*)d_ws;
  size_t off = 0;
  unsigned short* hb  = (unsigned short*)(p + off); off = align256(off + (size_t)Mpad * (HC1 > HC2 ? HC1 : HC2) * 2);
  unsigned short* xb  = (unsigned short*)(p + off); off = align256(off + (size_t)Mpad * K1pad * 2);
  unsigned short* xb2 = (unsigned short*)(p + off); off = align256(off + (size_t)Mpad * HC1 * 2);
  unsigned short* W1t = (unsigned short*)(p + off); off = align256(off + (size_t)HC1 * K1pad * 2);
  unsigned short* W2t = (unsigned short*)(p + off); off = align256(off + (size_t)HC2 * HC1 * 2);
  float* a_s   = (float*)(p + off); off = align256(off + (size_t)Nn * H * 4);
  float* a_d   = (float*)(p + off); off = align256(off + (size_t)Nn * H * 4);
  float* alpha = (float*)(p + off); off = align256(off + (size_t)Et * H * 4);
  int* cnt     = (int*)(p + off); off = align256(off + (size_t)Nn * 4);
  int* offs    = (int*)(p + off); off = align256(off + (size_t)(Nn + 1) * 4);
  int* fill    = (int*)(p + off); off = align256(off + (size_t)Nn * 4);
  int* srcs    = (int*)(p + off); off = align256(off + (size_t)Et * 4);
  int* flag64  = (int*)(p + off); off = align256(off + 16);
  (void)ws_size; (void)n_in; (void)out_size;

  const int TB = 256;
  // CSR build
  detect64_kernel<<<1, 1, 0, stream>>>((const unsigned int*)ei, flag64);
  init_cnt_kernel<<<(Nn + TB - 1) / TB, TB, 0, stream>>>(cnt, Nn);
  count_kernel<<<(E + TB - 1) / TB, TB, 0, stream>>>(ei, flag64, E, cnt);
  scan_kernel<<<1, 1024, 0, stream>>>(cnt, offs, Nn);
  init_self_kernel<<<(Nn + TB - 1) / TB, TB, 0, stream>>>(offs, srcs, fill, Nn);
  scatter_kernel<<<(E + TB - 1) / TB, TB, 0, stream>>>(ei, flag64, E, offs, fill, srcs);

  // bf16 casts
  {
    long chunks = (long)Nn * (K1pad >> 2);
    cast_pad_kernel<<<(int)((chunks + 255) / 256), 256, 0, stream>>>(x, xb, Nn, G, K1pad);
    dim3 g1(K1pad / 32, HC1 / 32);
    transpose_cast_kernel<<<g1, 256, 0, stream>>>(W1, W1t, G, HC1, K1pad);
    dim3 g2(HC1 / 32, HC2 / 32);
    transpose_cast_kernel<<<g2, 256, 0, stream>>>(W2, W2t, HC1, HC2, HC1);
  }

  // layer 1
  {
    dim3 grid(HC1 / 128, Mpad / 128);  // N-tile fastest
    mfma_gemm_kernel<unsigned short><<<grid, 320, 0, stream>>>(xb, W1t, hb, Nn, HC1, K1pad);
  }
  att_coef_kernel<<<(Nn + 3) / 4, 256, 0, stream>>>(hb, att_src1, att_dst1, a_s, a_d, Nn, H, C1);
  edge_softmax_kernel<<<(Nn * H + TB - 1) / TB, TB, 0, stream>>>(a_s, a_d, offs, srcs, alpha, Nn, H);
  aggregate1_kernel<<<Nn, 320, 0, stream>>>(hb, alpha, offs, srcs, b1, xb2, H, C1, HC1);

  // layer 2
  {
    dim3 grid(HC2 / 128, Mpad / 128);
    mfma_gemm_kernel<unsigned short><<<grid, 320, 0, stream>>>(xb2, W2t, hb, Nn, HC2, HC1);
  }
  att_coef_kernel<<<(Nn + 3) / 4, 256, 0, stream>>>(hb, att_src2, att_dst2, a_s, a_d, Nn, H, C2);
  edge_softmax_kernel<<<(Nn * H + TB - 1) / TB, TB, 0, stream>>>(a_s, a_d, offs, srcs, alpha, Nn, H);
  aggregate2_kernel<<<Nn, 128, 0, stream>>>(hb, alpha, offs, srcs, b2, out, H, C2);
}

// Round 8
// 1072.900 us; speedup vs baseline: 1.3282x; 1.2117x over previous
//
#include <hip/hip_runtime.h>

#define NEG_SLOPE 0.2f

typedef __attribute__((ext_vector_type(4))) float floatx4;
typedef __attribute__((ext_vector_type(8))) short shortx8;

__device__ __forceinline__ unsigned short f2bf(float f) {
  union { float f; unsigned int u; } v;
  v.f = f;
  unsigned int r = (v.u + 0x7FFFu + ((v.u >> 16) & 1u)) >> 16;
  return (unsigned short)r;
}
__device__ __forceinline__ float bf2f(unsigned short u) {
  union { unsigned int u; float f; } v;
  v.u = (unsigned int)u << 16;
  return v.f;
}
__device__ __forceinline__ void store_out(float* p, float v) { *p = v; }
__device__ __forceinline__ void store_out(unsigned short* p, float v) { *p = f2bf(v); }

// ---------------- edge index width detection (int32 vs int64) ----------------
__device__ __forceinline__ int load_edge(const void* ei, long idx, int is64) {
  if (is64) return (int)((const long long*)ei)[idx];
  return ((const int*)ei)[idx];
}

__global__ void detect64_kernel(const unsigned int* __restrict__ p, int* __restrict__ flag) {
  int is64 = 1;
  for (int i = 0; i < 32; ++i)
    if (p[2 * i + 1] != 0u) is64 = 0;
  *flag = is64;
}

// ---------------- CSR build ----------------
__global__ void init_cnt_kernel(int* __restrict__ cnt, int n) {
  int i = blockIdx.x * blockDim.x + threadIdx.x;
  if (i < n) cnt[i] = 1;  // self-loop
}

__global__ void count_kernel(const void* __restrict__ ei, const int* __restrict__ flag, int E,
                             int* __restrict__ cnt) {
  int e = blockIdx.x * blockDim.x + threadIdx.x;
  if (e >= E) return;
  int is64 = *flag;
  int d = load_edge(ei, (long)E + e, is64);
  atomicAdd(&cnt[d], 1);
}

__global__ __launch_bounds__(1024) void scan_kernel(const int* __restrict__ cnt,
                                                    int* __restrict__ offs, int n) {
  __shared__ int partial[1024];
  int t = threadIdx.x;
  int per = (n + 1023) / 1024;
  int beg = t * per;
  int end = min(beg + per, n);
  int sum = 0;
  for (int i = beg; i < end; ++i) sum += cnt[i];
  partial[t] = sum;
  __syncthreads();
  for (int d = 1; d < 1024; d <<= 1) {
    int v = (t >= d) ? partial[t - d] : 0;
    __syncthreads();
    partial[t] += v;
    __syncthreads();
  }
  int excl = (t == 0) ? 0 : partial[t - 1];
  for (int i = beg; i < end; ++i) { offs[i] = excl; excl += cnt[i]; }
  if (t == 1023) offs[n] = partial[1023];
}

__global__ void init_self_kernel(const int* __restrict__ offs, int* __restrict__ srcs,
                                 int* __restrict__ fill, int n) {
  int i = blockIdx.x * blockDim.x + threadIdx.x;
  if (i < n) { srcs[offs[i]] = i; fill[i] = 1; }
}

__global__ void scatter_kernel(const void* __restrict__ ei, const int* __restrict__ flag, int E,
                               const int* __restrict__ offs, int* __restrict__ fill,
                               int* __restrict__ srcs) {
  int e = blockIdx.x * blockDim.x + threadIdx.x;
  if (e >= E) return;
  int is64 = *flag;
  int s = load_edge(ei, e, is64);
  int d = load_edge(ei, (long)E + e, is64);
  int pos = offs[d] + atomicAdd(&fill[d], 1);
  srcs[pos] = s;
}

// ---------------- casts ----------------
__global__ __launch_bounds__(256) void cast_pad_kernel(const float* __restrict__ in,
                                                       unsigned short* __restrict__ out, int M,
                                                       int K, int Kpad) {
  long idx = (long)blockIdx.x * 256 + threadIdx.x;
  int cpr = Kpad >> 2;
  if (idx >= (long)M * cpr) return;
  int r = (int)(idx / cpr);
  int kc = (int)(idx - (long)r * cpr);
  int k = kc << 2;
  float4 v = make_float4(0.f, 0.f, 0.f, 0.f);
  if (k < K) v = *(const float4*)&in[(long)r * K + k];
  ushort4 o;
  o.x = f2bf(v.x); o.y = f2bf(v.y); o.z = f2bf(v.z); o.w = f2bf(v.w);
  *(ushort4*)&out[(long)r * Kpad + k] = o;
}

__global__ __launch_bounds__(256) void transpose_cast_kernel(const float* __restrict__ in,
                                                             unsigned short* __restrict__ out,
                                                             int K, int N, int Kpad) {
  __shared__ float tile[32][33];
  int kb = blockIdx.x * 32;
  int nb = blockIdx.y * 32;
  int tx = threadIdx.x & 31;
  int ty = threadIdx.x >> 5;
#pragma unroll
  for (int i = 0; i < 32; i += 8) {
    int k = kb + ty + i;
    tile[ty + i][tx] = (k < K) ? in[(long)k * N + nb + tx] : 0.f;
  }
  __syncthreads();
#pragma unroll
  for (int i = 0; i < 32; i += 8) {
    int n = nb + ty + i;
    out[(long)n * Kpad + kb + tx] = f2bf(tile[tx][ty + i]);
  }
}

// ---------------- bf16 MFMA GEMM — AITER-style reg-staged, RAW-barrier K-loop ----------------
// C[M,N] = A[M,K] * Bt[N,K]^T. Staging: buffer_load -> VGPR -> ds_write.
// Key: __builtin_amdgcn_s_barrier() is the bare instruction (no fence), so the
// next tile's register loads stay IN FLIGHT across the barrier — unlike
// __syncthreads, whose fence drains vmcnt(0) (the R2-R7 ~15% MfmaUtil wall).
// The backend's per-register scoreboard emits a precise vmcnt(4) at the
// ds_write consuming last iter's loads (never vmcnt 0). One explicit
// s_waitcnt lgkmcnt(0) (imm 0xC07F: vmcnt=63, expcnt=7, lgkmcnt=0) before the
// barrier makes my ds_writes visible to other waves.
// Hazard audit (1 barrier/iter, dbuf): iter-k pre-barrier writes slot k&1;
// lagging waves post-barrier of iter k-1 read slot (k-1)&1 (disjoint). A wave
// can only reach iter k+2's writes (slot k&1 again) after barrier k+1, which
// no wave passes until all iter-k reads retired (lgkm drained pre-barrier).
// Requires K%32==0, N%128==0, A allocated to gridDim.y*128 rows.
template <typename OT>
__global__ __launch_bounds__(256) void mfma_gemm_kernel(const unsigned short* __restrict__ A,
                                                        const unsigned short* __restrict__ Bt,
                                                        OT* __restrict__ C, int M, int N, int K) {
  __shared__ unsigned short As[2][4096];
  __shared__ unsigned short Bs[2][4096];

  int tid = threadIdx.x;
  int lane = tid & 63;
  int w = tid >> 6;
  int wm = w & 1, wn = w >> 1;
  int bn = blockIdx.x * 128;  // N-tile fastest (best FETCH: R3)
  int bm = blockIdx.y * 128;
  int quad = lane >> 4, l16 = lane & 15;

  // staging: thread -> row = tid&127, chunk pair {hi, hi+2}, hi = tid>>7
  int row = tid & 127;
  int hi = tid >> 7;
  const unsigned short* pA = A + (long)(bm + row) * K + hi * 8;
  const unsigned short* pB = Bt + (long)(bn + row) * K + hi * 8;
  int lds0 = (hi * 128 + row) * 8;  // chunk-major [kc][row][8]

  floatx4 acc[4][4];
#pragma unroll
  for (int i = 0; i < 4; ++i)
#pragma unroll
    for (int j = 0; j < 4; ++j) acc[i][j] = (floatx4){0.f, 0.f, 0.f, 0.f};

  uint4 sa0 = *(const uint4*)(pA);
  uint4 sa1 = *(const uint4*)(pA + 16);
  uint4 sb0 = *(const uint4*)(pB);
  uint4 sb1 = *(const uint4*)(pB + 16);

  int nk = K >> 5;
  for (int k = 0; k < nk; ++k) {
    int cur = k & 1;
    uint4 na0, na1, nb0, nb1;
    if (k + 1 < nk) {
      const unsigned short* qA = pA + ((k + 1) << 5);
      const unsigned short* qB = pB + ((k + 1) << 5);
      na0 = *(const uint4*)(qA);        // these fly across the barrier
      na1 = *(const uint4*)(qA + 16);
      nb0 = *(const uint4*)(qB);
      nb1 = *(const uint4*)(qB + 16);
    }
    // ds_write tile k (backend: precise vmcnt wait on sa*/sb* only)
    *(uint4*)&As[cur][lds0] = sa0;
    *(uint4*)&As[cur][lds0 + 2048] = sa1;  // chunk kc+2
    *(uint4*)&Bs[cur][lds0] = sb0;
    *(uint4*)&Bs[cur][lds0 + 2048] = sb1;
    __builtin_amdgcn_s_waitcnt(0xC07F);  // lgkmcnt(0) ONLY — ds_writes visible
    __builtin_amdgcn_s_barrier();        // bare barrier: vmcnt untouched
    shortx8 a[4], b[4];
#pragma unroll
    for (int i = 0; i < 4; ++i) {
      a[i] = *(const shortx8*)(&As[cur][(quad * 128 + wm * 64 + i * 16 + l16) * 8]);
      b[i] = *(const shortx8*)(&Bs[cur][(quad * 128 + wn * 64 + i * 16 + l16) * 8]);
    }
    sa0 = na0; sa1 = na1; sb0 = nb0; sb1 = nb1;
#pragma unroll
    for (int i = 0; i < 4; ++i)
#pragma unroll
      for (int j = 0; j < 4; ++j)
        acc[i][j] = __builtin_amdgcn_mfma_f32_16x16x32_bf16(a[i], b[j], acc[i][j], 0, 0, 0);
  }

  // epilogue: C/D layout col=lane&15, row=quad*4+reg
  int orow0 = bm + wm * 64 + quad * 4;
  int ocol0 = bn + wn * 64 + l16;
#pragma unroll
  for (int i = 0; i < 4; ++i)
#pragma unroll
    for (int j = 0; j < 4; ++j)
#pragma unroll
      for (int r = 0; r < 4; ++r) {
        int rr = orow0 + i * 16 + r;
        if (rr < M) store_out(&C[(long)rr * N + ocol0 + j * 16], acc[i][j][r]);
      }
}

// ---------------- attention coefficients from bf16 h ----------------
__global__ __launch_bounds__(256) void att_coef_kernel(const unsigned short* __restrict__ h,
                                                       const float* __restrict__ att_s,
                                                       const float* __restrict__ att_d,
                                                       float* __restrict__ a_s,
                                                       float* __restrict__ a_d, int n, int H,
                                                       int C) {
  int wave = (int)((blockIdx.x * blockDim.x + threadIdx.x) >> 6);
  int lane = threadIdx.x & 63;
  if (wave >= n) return;
  const unsigned short* row = h + (long)wave * H * C;
  for (int hh = 0; hh < H; ++hh) {
    float s = 0.f, d = 0.f;
    for (int c = lane; c < C; c += 64) {
      float v = bf2f(row[hh * C + c]);
      s += v * att_s[hh * C + c];
      d += v * att_d[hh * C + c];
    }
#pragma unroll
    for (int o = 32; o > 0; o >>= 1) {
      s += __shfl_down(s, o, 64);
      d += __shfl_down(d, o, 64);
    }
    if (lane == 0) {
      a_s[(long)wave * H + hh] = s;
      a_d[(long)wave * H + hh] = d;
    }
  }
}

// ---------------- per-(dst,head) segment softmax over CSR ----------------
__global__ void edge_softmax_kernel(const float* __restrict__ a_src,
                                    const float* __restrict__ a_dst,
                                    const int* __restrict__ offs, const int* __restrict__ srcs,
                                    float* __restrict__ alpha, int n, int H) {
  int idx = blockIdx.x * blockDim.x + threadIdx.x;
  if (idx >= n * H) return;
  int dstn = idx / H;
  int hh = idx - dstn * H;
  int beg = offs[dstn], end = offs[dstn + 1];
  float ad = a_dst[idx];
  float m = -1e30f;
  for (int j = beg; j < end; ++j) {
    float e = a_src[srcs[j] * H + hh] + ad;
    e = e > 0.f ? e : NEG_SLOPE * e;
    m = fmaxf(m, e);
  }
  float ssum = 0.f;
  for (int j = beg; j < end; ++j) {
    float e = a_src[srcs[j] * H + hh] + ad;
    e = e > 0.f ? e : NEG_SLOPE * e;
    float ex = __expf(e - m);
    alpha[(long)j * H + hh] = ex;
    ssum += ex;
  }
  float inv = 1.f / ssum;
  for (int j = beg; j < end; ++j) alpha[(long)j * H + hh] *= inv;
}

// ---------------- layer-1 aggregation: bf16 h -> bf16 x2, 16B vector loads ----------------
__global__ __launch_bounds__(320) void aggregate1_kernel(const unsigned short* __restrict__ h,
                                                         const float* __restrict__ alpha,
                                                         const int* __restrict__ offs,
                                                         const int* __restrict__ srcs,
                                                         const float* __restrict__ bias,
                                                         unsigned short* __restrict__ out, int H,
                                                         int C, int HC) {
  int dstn = blockIdx.x;
  int t = threadIdx.x;
  int beg = offs[dstn], end = offs[dstn + 1];
  int nf8 = HC >> 3;
  for (int fid = t; fid < nf8; fid += blockDim.x) {
    int hh = (fid << 3) / C;
    float acc[8];
#pragma unroll
    for (int i = 0; i < 8; ++i) acc[i] = 0.f;
    for (int j = beg; j < end; ++j) {
      int s = srcs[j];
      float al = alpha[(long)j * H + hh];
      shortx8 r = ((const shortx8*)(h + (long)s * HC))[fid];
#pragma unroll
      for (int i = 0; i < 8; ++i) acc[i] = fmaf(al, bf2f((unsigned short)r[i]), acc[i]);
    }
    shortx8 o;
#pragma unroll
    for (int i = 0; i < 8; ++i) {
      float bb = bias[(fid << 3) + i];
      o[i] = (short)f2bf(fmaxf(acc[i] + bb, 0.f));
    }
    ((shortx8*)(out + (long)dstn * HC))[fid] = o;
  }
}

// ---------------- layer-2 aggregation with head-mean: bf16 h -> fp32 out ----------------
__global__ __launch_bounds__(128) void aggregate2_kernel(const unsigned short* __restrict__ h,
                                                         const float* __restrict__ alpha,
                                                         const int* __restrict__ offs,
                                                         const int* __restrict__ srcs,
                                                         const float* __restrict__ bias,
                                                         float* __restrict__ out, int H, int C) {
  int dstn = blockIdx.x;
  int c = threadIdx.x;
  if (c >= C) return;
  int beg = offs[dstn], end = offs[dstn + 1];
  int HC = H * C;
  float acc = 0.f;
  for (int j = beg; j < end; ++j) {
    int s = srcs[j];
    const unsigned short* row = h + (long)s * HC;
    const float* al = alpha + (long)j * H;
#pragma unroll 5
    for (int hh = 0; hh < H; ++hh) acc = fmaf(al[hh], bf2f(row[hh * C + c]), acc);
  }
  float v = acc * (1.f / (float)H) + bias[c];
  out[(long)dstn * C + c] = v > 0.f ? v : 0.f;
}

// ---------------- host ----------------
static inline size_t align256(size_t x) { return (x + 255) & ~(size_t)255; }

extern "C" void kernel_launch(void* const* d_in, const int* in_sizes, int n_in, void* d_out,
                              int out_size, void* d_ws, size_t ws_size, hipStream_t stream) {
  const float* x        = (const float*)d_in[0];
  const void*  ei       = d_in[1];
  const float* W1       = (const float*)d_in[2];
  const float* att_src1 = (const float*)d_in[3];
  const float* att_dst1 = (const float*)d_in[4];
  const float* b1       = (const float*)d_in[5];
  const float* W2       = (const float*)d_in[6];
  const float* att_src2 = (const float*)d_in[7];
  const float* att_dst2 = (const float*)d_in[8];
  const float* b2       = (const float*)d_in[9];
  float* out = (float*)d_out;

  const int C2  = in_sizes[9];       // 128
  const int H   = in_sizes[7] / C2;  // 20
  const int HC1 = in_sizes[5];       // 2560
  const int C1  = HC1 / H;           // 128
  const int G   = in_sizes[2] / HC1; // 2000
  const int Nn  = in_sizes[0] / G;   // 10000
  const int E   = in_sizes[1] / 2;   // 100000
  const int HC2 = H * C2;            // 2560
  const int Et  = E + Nn;
  const int Mpad = ((Nn + 127) / 128) * 128;
  const int K1pad = ((G + 31) / 32) * 32;  // 2048

  // workspace layout
  char* p = (char*)d_ws;
  size_t off = 0;
  unsigned short* hb  = (unsigned short*)(p + off); off = align256(off + (size_t)Mpad * (HC1 > HC2 ? HC1 : HC2) * 2);
  unsigned short* xb  = (unsigned short*)(p + off); off = align256(off + (size_t)Mpad * K1pad * 2);
  unsigned short* xb2 = (unsigned short*)(p + off); off = align256(off + (size_t)Mpad * HC1 * 2);
  unsigned short* W1t = (unsigned short*)(p + off); off = align256(off + (size_t)HC1 * K1pad * 2);
  unsigned short* W2t = (unsigned short*)(p + off); off = align256(off + (size_t)HC2 * HC1 * 2);
  float* a_s   = (float*)(p + off); off = align256(off + (size_t)Nn * H * 4);
  float* a_d   = (float*)(p + off); off = align256(off + (size_t)Nn * H * 4);
  float* alpha = (float*)(p + off); off = align256(off + (size_t)Et * H * 4);
  int* cnt     = (int*)(p + off); off = align256(off + (size_t)Nn * 4);
  int* offs    = (int*)(p + off); off = align256(off + (size_t)(Nn + 1) * 4);
  int* fill    = (int*)(p + off); off = align256(off + (size_t)Nn * 4);
  int* srcs    = (int*)(p + off); off = align256(off + (size_t)Et * 4);
  int* flag64  = (int*)(p + off); off = align256(off + 16);
  (void)ws_size; (void)n_in; (void)out_size;

  const int TB = 256;
  // CSR build
  detect64_kernel<<<1, 1, 0, stream>>>((const unsigned int*)ei, flag64);
  init_cnt_kernel<<<(Nn + TB - 1) / TB, TB, 0, stream>>>(cnt, Nn);
  count_kernel<<<(E + TB - 1) / TB, TB, 0, stream>>>(ei, flag64, E, cnt);
  scan_kernel<<<1, 1024, 0, stream>>>(cnt, offs, Nn);
  init_self_kernel<<<(Nn + TB - 1) / TB, TB, 0, stream>>>(offs, srcs, fill, Nn);
  scatter_kernel<<<(E + TB - 1) / TB, TB, 0, stream>>>(ei, flag64, E, offs, fill, srcs);

  // bf16 casts
  {
    long chunks = (long)Nn * (K1pad >> 2);
    cast_pad_kernel<<<(int)((chunks + 255) / 256), 256, 0, stream>>>(x, xb, Nn, G, K1pad);
    dim3 g1(K1pad / 32, HC1 / 32);
    transpose_cast_kernel<<<g1, 256, 0, stream>>>(W1, W1t, G, HC1, K1pad);
    dim3 g2(HC1 / 32, HC2 / 32);
    transpose_cast_kernel<<<g2, 256, 0, stream>>>(W2, W2t, HC1, HC2, HC1);
  }

  // layer 1
  {
    dim3 grid(HC1 / 128, Mpad / 128);  // N-tile fastest
    mfma_gemm_kernel<unsigned short><<<grid, 256, 0, stream>>>(xb, W1t, hb, Nn, HC1, K1pad);
  }
  att_coef_kernel<<<(Nn + 3) / 4, 256, 0, stream>>>(hb, att_src1, att_dst1, a_s, a_d, Nn, H, C1);
  edge_softmax_kernel<<<(Nn * H + TB - 1) / TB, TB, 0, stream>>>(a_s, a_d, offs, srcs, alpha, Nn, H);
  aggregate1_kernel<<<Nn, 320, 0, stream>>>(hb, alpha, offs, srcs, b1, xb2, H, C1, HC1);

  // layer 2
  {
    dim3 grid(HC2 / 128, Mpad / 128);
    mfma_gemm_kernel<unsigned short><<<grid, 256, 0, stream>>>(xb2, W2t, hb, Nn, HC2, HC1);
  }
  att_coef_kernel<<<(Nn + 3) / 4, 256, 0, stream>>>(hb, att_src2, att_dst2, a_s, a_d, Nn, H, C2);
  edge_softmax_kernel<<<(Nn * H + TB - 1) / TB, TB, 0, stream>>>(a_s, a_d, offs, srcs, alpha, Nn, H);
  aggregate2_kernel<<<Nn, 128, 0, stream>>>(hb, alpha, offs, srcs, b2, out, H, C2);
}